// Round 23
// baseline (2933.163 us; speedup 1.0000x reference)
//
#include <hip/hip_runtime.h>
#include <hip/hip_bf16.h>
#include <math.h>

// Shapes: B=256, T=1024, F=128, D=256, UNITS=64. Inputs f32; out f32 [B,T,D].
//
// FROZEN arithmetic (r17+, absmax=0.0 bit-exact): sequential ascending-k fmaf
// chains, u=(mm1+mm2)+bias, z=fmaf(sh,u,h1), XLA EmitFastTanh.
// r22 post-mortem: 8-deep LDS window = reuse distance 48-64 cyc < ~120 cyc
// LDS latency at 1 wave/SIMD -> per-reload stalls (VALUBusy 84.8->46%).
// r23: ALL multipliers via broadcast ds_read_b128 with a 32-deep rolling
// window (reuse distance ~256 issue-cyc >> latency). Zero readlanes, zero
// SGPR hazards. Window statically indexed under full unroll (rule #20).

__device__ __forceinline__ float xla_tanh(float x) {
    const float kClamp = 7.99881172180175781f;
    float xc = fminf(fmaxf(x, -kClamp), kClamp);
    float x2 = xc * xc;
    float num = -2.76076847742355e-16f;
    num = fmaf(x2, num, 2.00018790482477e-13f);
    num = fmaf(x2, num, -8.60467152213735e-11f);
    num = fmaf(x2, num, 5.12229709037114e-08f);
    num = fmaf(x2, num, 1.48572235717979e-05f);
    num = fmaf(x2, num, 6.37261928875436e-04f);
    num = fmaf(x2, num, 4.89352455891786e-03f);
    num = xc * num;
    float den = 1.19825839466702e-06f;
    den = fmaf(x2, den, 1.18534705686654e-04f);
    den = fmaf(x2, den, 2.26843463243900e-03f);
    den = fmaf(x2, den, 4.89352518554385e-03f);
    return (fabsf(x) < 0.0004f) ? x : (num / den);
}

// ---------------- Phase 1: mm1[b,t,d] = dx_t @ K[:,d] (raw, no bias) -------
__global__ __launch_bounds__(256, 2)
void lrs_mm1(const float* __restrict__ x, const float* __restrict__ K,
             float* __restrict__ out) {
    const int d = threadIdx.x;
    float kc[128];
#pragma unroll
    for (int j = 0; j < 128; ++j) kc[j] = K[j * 256 + d];

    __shared__ __align__(16) float dx2[2][128];
    const int m0 = blockIdx.x * 256;          // grid 1024, 256 rows/block
    for (int mm = m0; mm < m0 + 256; mm += 2) {
        __syncthreads();                      // protect dx2 reuse
        if (d < 128) {                        // stage row mm
            const float xa  = x[(size_t)mm * 128 + d];
            const float xpa = (mm & 1023) ? x[(size_t)(mm - 1) * 128 + d] : 0.0f;
            dx2[0][d] = xa - xpa;             // f32 sub (= ref)
        } else {                              // stage row mm+1
            const int dd = d - 128;
            const float xb  = x[(size_t)(mm + 1) * 128 + dd];
            const float xpb = ((mm + 1) & 1023) ? x[(size_t)mm * 128 + dd] : 0.0f;
            dx2[1][dd] = xb - xpb;
        }
        __syncthreads();

        float a0 = 0.0f, a1 = 0.0f;
#pragma unroll
        for (int j = 0; j < 128; j += 4) {
            const float4 v0 = *reinterpret_cast<const float4*>(&dx2[0][j]);
            const float4 v1 = *reinterpret_cast<const float4*>(&dx2[1][j]);
            a0 = fmaf(v0.x, kc[j + 0], a0);  a1 = fmaf(v1.x, kc[j + 0], a1);
            a0 = fmaf(v0.y, kc[j + 1], a0);  a1 = fmaf(v1.y, kc[j + 1], a1);
            a0 = fmaf(v0.z, kc[j + 2], a0);  a1 = fmaf(v1.z, kc[j + 2], a1);
            a0 = fmaf(v0.w, kc[j + 3], a0);  a1 = fmaf(v1.w, kc[j + 3], a1);
        }
        out[(size_t)mm * 256 + d]       = a0;
        out[(size_t)(mm + 1) * 256 + d] = a1;
    }
}

// ---------------- Phase 2: recurrence ---------------------------------------
__global__ __launch_bounds__(256, 1)
void lrs_rec(const float* __restrict__ R, const float* __restrict__ bias,
             float* __restrict__ out) {
    const int b = blockIdx.x;      // grid = 256, one batch row per block/CU
    const int d = threadIdx.x;     // one output column per thread

    __shared__ __align__(16) float dh0[256], dh1[256];
    __shared__ __align__(16) float h10[256], h11[256];

    float rcf[256];                // R[:,d]; read-only -> AGPR-friendly
#pragma unroll
    for (int i = 0; i < 256; ++i) rcf[i] = R[(size_t)i * 256 + d];
    const float bd = bias[d];      // zeros in this problem

    dh0[d] = 0.0f;
    h10[d] = 0.0f;
    float h1 = 0.0f;
    __syncthreads();

    float* orow = out + (size_t)b * (1024 * 256);
    float u1 = orow[d];            // mm1 for t=0 (phase-1 result)

    const float* dhc = dh0; float* dhn = dh1;
    const float* h1c = h10; float* h1n = h11;

    for (int t = 0; t < 1024; ++t) {
        const float u1n = (t < 1023) ? orow[(t + 1) * 256 + d] : 0.0f;
        const float sh  = (d < 64) ? 1.0f : h1c[d - 64];

        // ---- 32-deep rolling window of broadcast ds_read_b128 ----
        const float4* dh4 = reinterpret_cast<const float4*>(dhc);
        float4 w[32];              // statically indexed only (stays in VGPRs)
#pragma unroll
        for (int g = 0; g < 32; ++g) w[g] = dh4[g];

        // mm2: single sequential ascending-i fmaf chain (bit-exact order)
        float acc = 0.0f;
#pragma unroll
        for (int g = 0; g < 64; ++g) {
            const float4 v = w[g & 31];
            if (g < 32) w[g] = dh4[g + 32];   // reload: reused 32 groups later
            acc = fmaf(v.x, rcf[4 * g + 0], acc);
            acc = fmaf(v.y, rcf[4 * g + 1], acc);
            acc = fmaf(v.z, rcf[4 * g + 2], acc);
            acc = fmaf(v.w, rcf[4 * g + 3], acc);
        }

        const float u  = (u1 + acc) + bd;     // (mm1 + mm2) + bias
        const float z  = fmaf(sh, u, h1);
        const float hn = xla_tanh(z);

        orow[t * 256 + d] = hn;               // fire-and-forget store

        dhn[d] = hn - h1;                     // publish into the other buffer
        h1n[d] = hn;
        h1 = hn; u1 = u1n;

        const float* tp = dhc; dhc = dhn; dhn = (float*)tp;
        tp = h1c; h1c = h1n; h1n = (float*)tp;
        __syncthreads();                      // single barrier per step
    }
}

extern "C" void kernel_launch(void* const* d_in, const int* in_sizes, int n_in,
                              void* d_out, int out_size, void* d_ws, size_t ws_size,
                              hipStream_t stream) {
    // Size-based mapping (element counts); fallback to dict order.
    const float* x = nullptr; const float* K = nullptr;
    const float* R = nullptr; const float* bias = nullptr;
    for (int i = 0; i < n_in; ++i) {
        switch (in_sizes[i]) {
            case 33554432: x    = (const float*)d_in[i]; break;
            case 32768:    K    = (const float*)d_in[i]; break;
            case 65536:    R    = (const float*)d_in[i]; break;
            case 256:      bias = (const float*)d_in[i]; break;
            default: break;
        }
    }
    if (!x || !K || !R || !bias) {
        x    = (const float*)d_in[0];
        K    = (const float*)d_in[1];
        R    = (const float*)d_in[2];
        bias = (const float*)d_in[3];
    }
    float* out = (float*)d_out;

    lrs_mm1<<<1024, 256, 0, stream>>>(x, K, out);
    lrs_rec<<<256, 256, 0, stream>>>(R, bias, out);
}

// Round 24
// 2928.223 us; speedup vs baseline: 1.0017x; 1.0017x over previous
//
#include <hip/hip_runtime.h>
#include <hip/hip_bf16.h>
#include <math.h>

// Shapes: B=256, T=1024, F=128, D=256, UNITS=64. Inputs f32; out f32 [B,T,D].
//
// FROZEN arithmetic (r17+, absmax=0.0 bit-exact): sequential ascending-k fmaf
// chains, u=(mm1+mm2)+bias, z=fmaf(sh,u,h1), XLA EmitFastTanh.
// r23 post-mortem: w[32] float4 (128 VGPR) + rcf[256] > 256 arch-VGPR limit
// (AGPR shuffling) AND 32 outstanding ds_reads > lgkmcnt max 15 (forced
// conservative waits) -> VALUBusy 21%. r24: window = 12 float4 = 48 VGPR,
// 12 lgkm events <= 15, reuse distance ~192 cyc > ~120 cyc LDS latency;
// b128 delivers 4 multipliers per lgkm event so the counter cap no longer
// throttles the chain. Same FMA order -> bit-exact.

__device__ __forceinline__ float xla_tanh(float x) {
    const float kClamp = 7.99881172180175781f;
    float xc = fminf(fmaxf(x, -kClamp), kClamp);
    float x2 = xc * xc;
    float num = -2.76076847742355e-16f;
    num = fmaf(x2, num, 2.00018790482477e-13f);
    num = fmaf(x2, num, -8.60467152213735e-11f);
    num = fmaf(x2, num, 5.12229709037114e-08f);
    num = fmaf(x2, num, 1.48572235717979e-05f);
    num = fmaf(x2, num, 6.37261928875436e-04f);
    num = fmaf(x2, num, 4.89352455891786e-03f);
    num = xc * num;
    float den = 1.19825839466702e-06f;
    den = fmaf(x2, den, 1.18534705686654e-04f);
    den = fmaf(x2, den, 2.26843463243900e-03f);
    den = fmaf(x2, den, 4.89352518554385e-03f);
    return (fabsf(x) < 0.0004f) ? x : (num / den);
}

// ---------------- Phase 1: mm1[b,t,d] = dx_t @ K[:,d] (raw, no bias) -------
__global__ __launch_bounds__(256, 2)
void lrs_mm1(const float* __restrict__ x, const float* __restrict__ K,
             float* __restrict__ out) {
    const int d = threadIdx.x;
    float kc[128];
#pragma unroll
    for (int j = 0; j < 128; ++j) kc[j] = K[j * 256 + d];

    __shared__ __align__(16) float dx2[2][128];
    const int m0 = blockIdx.x * 256;          // grid 1024, 256 rows/block
    for (int mm = m0; mm < m0 + 256; mm += 2) {
        __syncthreads();                      // protect dx2 reuse
        if (d < 128) {                        // stage row mm
            const float xa  = x[(size_t)mm * 128 + d];
            const float xpa = (mm & 1023) ? x[(size_t)(mm - 1) * 128 + d] : 0.0f;
            dx2[0][d] = xa - xpa;             // f32 sub (= ref)
        } else {                              // stage row mm+1
            const int dd = d - 128;
            const float xb  = x[(size_t)(mm + 1) * 128 + dd];
            const float xpb = ((mm + 1) & 1023) ? x[(size_t)mm * 128 + dd] : 0.0f;
            dx2[1][dd] = xb - xpb;
        }
        __syncthreads();

        float a0 = 0.0f, a1 = 0.0f;
#pragma unroll
        for (int j = 0; j < 128; j += 4) {
            const float4 v0 = *reinterpret_cast<const float4*>(&dx2[0][j]);
            const float4 v1 = *reinterpret_cast<const float4*>(&dx2[1][j]);
            a0 = fmaf(v0.x, kc[j + 0], a0);  a1 = fmaf(v1.x, kc[j + 0], a1);
            a0 = fmaf(v0.y, kc[j + 1], a0);  a1 = fmaf(v1.y, kc[j + 1], a1);
            a0 = fmaf(v0.z, kc[j + 2], a0);  a1 = fmaf(v1.z, kc[j + 2], a1);
            a0 = fmaf(v0.w, kc[j + 3], a0);  a1 = fmaf(v1.w, kc[j + 3], a1);
        }
        out[(size_t)mm * 256 + d]       = a0;
        out[(size_t)(mm + 1) * 256 + d] = a1;
    }
}

// ---------------- Phase 2: recurrence ---------------------------------------
#define WIN 12
__global__ __launch_bounds__(256, 1)
void lrs_rec(const float* __restrict__ R, const float* __restrict__ bias,
             float* __restrict__ out) {
    const int b = blockIdx.x;      // grid = 256, one batch row per block/CU
    const int d = threadIdx.x;     // one output column per thread

    __shared__ __align__(16) float dh0[256], dh1[256];
    __shared__ __align__(16) float h10[256], h11[256];

    float rcf[256];                // R[:,d]; read-only -> lives in AGPRs
#pragma unroll
    for (int i = 0; i < 256; ++i) rcf[i] = R[(size_t)i * 256 + d];
    const float bd = bias[d];      // zeros in this problem

    dh0[d] = 0.0f;
    h10[d] = 0.0f;
    float h1 = 0.0f;
    __syncthreads();

    float* orow = out + (size_t)b * (1024 * 256);
    float u1 = orow[d];            // mm1 for t=0 (phase-1 result)

    const float* dhc = dh0; float* dhn = dh1;
    const float* h1c = h10; float* h1n = h11;

    for (int t = 0; t < 1024; ++t) {
        const float u1n = (t < 1023) ? orow[(t + 1) * 256 + d] : 0.0f;
        const float sh  = (d < 64) ? 1.0f : h1c[d - 64];

        // ---- WIN-deep rolling window of broadcast ds_read_b128 ----
        const float4* dh4 = reinterpret_cast<const float4*>(dhc);
        float4 w[WIN];             // 48 VGPRs, statically indexed (rule #20)
#pragma unroll
        for (int g = 0; g < WIN; ++g) w[g] = dh4[g];

        // mm2: single sequential ascending-i fmaf chain (bit-exact order)
        float acc = 0.0f;
#pragma unroll
        for (int g = 0; g < 64; ++g) {
            const float4 v = w[g % WIN];
            if (g + WIN < 64) w[g % WIN] = dh4[g + WIN];  // refill: reused
            acc = fmaf(v.x, rcf[4 * g + 0], acc);         // WIN groups later
            acc = fmaf(v.y, rcf[4 * g + 1], acc);
            acc = fmaf(v.z, rcf[4 * g + 2], acc);
            acc = fmaf(v.w, rcf[4 * g + 3], acc);
        }

        const float u  = (u1 + acc) + bd;     // (mm1 + mm2) + bias
        const float z  = fmaf(sh, u, h1);
        const float hn = xla_tanh(z);

        dhn[d] = hn - h1;                     // publish first (critical path)
        h1n[d] = hn;
        orow[t * 256 + d] = hn;               // fire-and-forget store
        h1 = hn; u1 = u1n;

        const float* tp = dhc; dhc = dhn; dhn = (float*)tp;
        tp = h1c; h1c = h1n; h1n = (float*)tp;
        __syncthreads();                      // single barrier per step
    }
}
#undef WIN

extern "C" void kernel_launch(void* const* d_in, const int* in_sizes, int n_in,
                              void* d_out, int out_size, void* d_ws, size_t ws_size,
                              hipStream_t stream) {
    // Size-based mapping (element counts); fallback to dict order.
    const float* x = nullptr; const float* K = nullptr;
    const float* R = nullptr; const float* bias = nullptr;
    for (int i = 0; i < n_in; ++i) {
        switch (in_sizes[i]) {
            case 33554432: x    = (const float*)d_in[i]; break;
            case 32768:    K    = (const float*)d_in[i]; break;
            case 65536:    R    = (const float*)d_in[i]; break;
            case 256:      bias = (const float*)d_in[i]; break;
            default: break;
        }
    }
    if (!x || !K || !R || !bias) {
        x    = (const float*)d_in[0];
        K    = (const float*)d_in[1];
        R    = (const float*)d_in[2];
        bias = (const float*)d_in[3];
    }
    float* out = (float*)d_out;

    lrs_mm1<<<1024, 256, 0, stream>>>(x, K, out);
    lrs_rec<<<256, 256, 0, stream>>>(R, bias, out);
}

// Round 25
// 2923.215 us; speedup vs baseline: 1.0034x; 1.0017x over previous
//
#include <hip/hip_runtime.h>
#include <hip/hip_bf16.h>
#include <math.h>

// Shapes: B=256, T=1024, F=128, D=256, UNITS=64. Inputs f32; out f32 [B,T,D].
//
// FROZEN arithmetic (r17+, absmax=0.0 bit-exact): sequential ascending-k fmaf
// chains, u=(mm1+mm2)+bias, z=fmaf(sh,u,h1), XLA EmitFastTanh.
// r23/r24 post-mortem: w[g % WIN] under pragma-unroll was NOT static ->
// window in scratch (L2-resident, invisible in FETCH; VGPR_Count 140,
// VALUBusy 21%). r22 proved NAMED float4 window stays in VGPRs; its only
// flaw was 8-deep (reuse 80cyc < 120cyc LDS latency).
// r25: 16 NAMED window regs w0..w15, 64 explicitly expanded groups, refill
// distance 16 groups (~160 cyc). Zero readlanes. Same FMA order -> bit-exact.

__device__ __forceinline__ float xla_tanh(float x) {
    const float kClamp = 7.99881172180175781f;
    float xc = fminf(fmaxf(x, -kClamp), kClamp);
    float x2 = xc * xc;
    float num = -2.76076847742355e-16f;
    num = fmaf(x2, num, 2.00018790482477e-13f);
    num = fmaf(x2, num, -8.60467152213735e-11f);
    num = fmaf(x2, num, 5.12229709037114e-08f);
    num = fmaf(x2, num, 1.48572235717979e-05f);
    num = fmaf(x2, num, 6.37261928875436e-04f);
    num = fmaf(x2, num, 4.89352455891786e-03f);
    num = xc * num;
    float den = 1.19825839466702e-06f;
    den = fmaf(x2, den, 1.18534705686654e-04f);
    den = fmaf(x2, den, 2.26843463243900e-03f);
    den = fmaf(x2, den, 4.89352518554385e-03f);
    return (fabsf(x) < 0.0004f) ? x : (num / den);
}

// ---------------- Phase 1: mm1[b,t,d] = dx_t @ K[:,d] (raw, no bias) -------
__global__ __launch_bounds__(256, 2)
void lrs_mm1(const float* __restrict__ x, const float* __restrict__ K,
             float* __restrict__ out) {
    const int d = threadIdx.x;
    float kc[128];
#pragma unroll
    for (int j = 0; j < 128; ++j) kc[j] = K[j * 256 + d];

    __shared__ __align__(16) float dx2[2][128];
    const int m0 = blockIdx.x * 256;          // grid 1024, 256 rows/block
    for (int mm = m0; mm < m0 + 256; mm += 2) {
        __syncthreads();                      // protect dx2 reuse
        if (d < 128) {                        // stage row mm
            const float xa  = x[(size_t)mm * 128 + d];
            const float xpa = (mm & 1023) ? x[(size_t)(mm - 1) * 128 + d] : 0.0f;
            dx2[0][d] = xa - xpa;             // f32 sub (= ref)
        } else {                              // stage row mm+1
            const int dd = d - 128;
            const float xb  = x[(size_t)(mm + 1) * 128 + dd];
            const float xpb = ((mm + 1) & 1023) ? x[(size_t)mm * 128 + dd] : 0.0f;
            dx2[1][dd] = xb - xpb;
        }
        __syncthreads();

        float a0 = 0.0f, a1 = 0.0f;
#pragma unroll
        for (int j = 0; j < 128; j += 4) {
            const float4 v0 = *reinterpret_cast<const float4*>(&dx2[0][j]);
            const float4 v1 = *reinterpret_cast<const float4*>(&dx2[1][j]);
            a0 = fmaf(v0.x, kc[j + 0], a0);  a1 = fmaf(v1.x, kc[j + 0], a1);
            a0 = fmaf(v0.y, kc[j + 1], a0);  a1 = fmaf(v1.y, kc[j + 1], a1);
            a0 = fmaf(v0.z, kc[j + 2], a0);  a1 = fmaf(v1.z, kc[j + 2], a1);
            a0 = fmaf(v0.w, kc[j + 3], a0);  a1 = fmaf(v1.w, kc[j + 3], a1);
        }
        out[(size_t)mm * 256 + d]       = a0;
        out[(size_t)(mm + 1) * 256 + d] = a1;
    }
}

// ---------------- Phase 2: recurrence ---------------------------------------
__global__ __launch_bounds__(256, 1)
void lrs_rec(const float* __restrict__ R, const float* __restrict__ bias,
             float* __restrict__ out) {
    const int b = blockIdx.x;      // grid = 256, one batch row per block/CU
    const int d = threadIdx.x;     // one output column per thread

    __shared__ __align__(16) float dh0[256], dh1[256];
    __shared__ __align__(16) float h10[256], h11[256];

    float rcf[256];                // R[:,d]; overflow lives in AGPRs
#pragma unroll
    for (int i = 0; i < 256; ++i) rcf[i] = R[(size_t)i * 256 + d];
    const float bd = bias[d];      // zeros in this problem

    dh0[d] = 0.0f;
    h10[d] = 0.0f;
    float h1 = 0.0f;
    __syncthreads();

    float* orow = out + (size_t)b * (1024 * 256);
    float u1 = orow[d];            // mm1 for t=0 (phase-1 result)

    const float* dhc = dh0; float* dhn = dh1;
    const float* h1c = h10; float* h1n = h11;

    for (int t = 0; t < 1024; ++t) {
        const float u1n = (t < 1023) ? orow[(t + 1) * 256 + d] : 0.0f;
        const float sh  = (d < 64) ? 1.0f : h1c[d - 64];

        // prime 16 NAMED window regs (64 VGPRs, all static — rule #20 safe)
        const float4* dh4 = reinterpret_cast<const float4*>(dhc);
        float4 w0  = dh4[0],  w1  = dh4[1],  w2  = dh4[2],  w3  = dh4[3];
        float4 w4  = dh4[4],  w5  = dh4[5],  w6  = dh4[6],  w7  = dh4[7];
        float4 w8  = dh4[8],  w9  = dh4[9],  w10 = dh4[10], w11 = dh4[11];
        float4 w12 = dh4[12], w13 = dh4[13], w14 = dh4[14], w15 = dh4[15];

        // mm2: single sequential ascending-i fmaf chain (bit-exact order).
        // Use-then-refill, distance 16 groups (~160 cyc > ~120 cyc latency).
        float acc = 0.0f;
#define GU(W, G)                                                              \
        acc = fmaf(W.x, rcf[4 * (G) + 0], acc);                               \
        acc = fmaf(W.y, rcf[4 * (G) + 1], acc);                               \
        acc = fmaf(W.z, rcf[4 * (G) + 2], acc);                               \
        acc = fmaf(W.w, rcf[4 * (G) + 3], acc);
#define GR(W, G, L)  GU(W, G)  W = dh4[(L)];
        GR(w0,  0, 16) GR(w1,  1, 17) GR(w2,  2, 18) GR(w3,  3, 19)
        GR(w4,  4, 20) GR(w5,  5, 21) GR(w6,  6, 22) GR(w7,  7, 23)
        GR(w8,  8, 24) GR(w9,  9, 25) GR(w10, 10, 26) GR(w11, 11, 27)
        GR(w12, 12, 28) GR(w13, 13, 29) GR(w14, 14, 30) GR(w15, 15, 31)
        GR(w0, 16, 32) GR(w1, 17, 33) GR(w2, 18, 34) GR(w3, 19, 35)
        GR(w4, 20, 36) GR(w5, 21, 37) GR(w6, 22, 38) GR(w7, 23, 39)
        GR(w8, 24, 40) GR(w9, 25, 41) GR(w10, 26, 42) GR(w11, 27, 43)
        GR(w12, 28, 44) GR(w13, 29, 45) GR(w14, 30, 46) GR(w15, 31, 47)
        GR(w0, 32, 48) GR(w1, 33, 49) GR(w2, 34, 50) GR(w3, 35, 51)
        GR(w4, 36, 52) GR(w5, 37, 53) GR(w6, 38, 54) GR(w7, 39, 55)
        GR(w8, 40, 56) GR(w9, 41, 57) GR(w10, 42, 58) GR(w11, 43, 59)
        GR(w12, 44, 60) GR(w13, 45, 61) GR(w14, 46, 62) GR(w15, 47, 63)
        GU(w0, 48) GU(w1, 49) GU(w2, 50) GU(w3, 51)
        GU(w4, 52) GU(w5, 53) GU(w6, 54) GU(w7, 55)
        GU(w8, 56) GU(w9, 57) GU(w10, 58) GU(w11, 59)
        GU(w12, 60) GU(w13, 61) GU(w14, 62) GU(w15, 63)
#undef GR
#undef GU

        const float u  = (u1 + acc) + bd;     // (mm1 + mm2) + bias
        const float z  = fmaf(sh, u, h1);
        const float hn = xla_tanh(z);

        dhn[d] = hn - h1;                     // publish first (critical path)
        h1n[d] = hn;
        orow[t * 256 + d] = hn;               // fire-and-forget store
        h1 = hn; u1 = u1n;

        const float* tp = dhc; dhc = dhn; dhn = (float*)tp;
        tp = h1c; h1c = h1n; h1n = (float*)tp;
        __syncthreads();                      // single barrier per step
    }
}

extern "C" void kernel_launch(void* const* d_in, const int* in_sizes, int n_in,
                              void* d_out, int out_size, void* d_ws, size_t ws_size,
                              hipStream_t stream) {
    // Size-based mapping (element counts); fallback to dict order.
    const float* x = nullptr; const float* K = nullptr;
    const float* R = nullptr; const float* bias = nullptr;
    for (int i = 0; i < n_in; ++i) {
        switch (in_sizes[i]) {
            case 33554432: x    = (const float*)d_in[i]; break;
            case 32768:    K    = (const float*)d_in[i]; break;
            case 65536:    R    = (const float*)d_in[i]; break;
            case 256:      bias = (const float*)d_in[i]; break;
            default: break;
        }
    }
    if (!x || !K || !R || !bias) {
        x    = (const float*)d_in[0];
        K    = (const float*)d_in[1];
        R    = (const float*)d_in[2];
        bias = (const float*)d_in[3];
    }
    float* out = (float*)d_out;

    lrs_mm1<<<1024, 256, 0, stream>>>(x, K, out);
    lrs_rec<<<256, 256, 0, stream>>>(R, bias, out);
}

// Round 26
// 1666.034 us; speedup vs baseline: 1.7606x; 1.7546x over previous
//
#include <hip/hip_runtime.h>
#include <hip/hip_bf16.h>
#include <math.h>

// Shapes: B=256, T=1024, F=128, D=256, UNITS=64. Inputs f32; out f32 [B,T,D].
//
// FROZEN arithmetic (r17+, absmax=0.0 bit-exact): sequential ascending-k fmaf
// chains, u=(mm1+mm2)+bias, z=fmaf(sh,u,h1), XLA EmitFastTanh.
// r23-r25 post-mortem: identical counters across 3 source-level window
// variants -> hipcc canonicalizes and inserts conservative lgkm waits;
// source scheduling is dead. r26: inline-asm ds_read_b128 stream with
// MANUAL counted s_waitcnt lgkmcnt(N) + sched_barrier(0) (rule #18),
// 12-deep named float4 window. FMA chain stays pure HIP in frozen order.

__device__ __forceinline__ float xla_tanh(float x) {
    const float kClamp = 7.99881172180175781f;
    float xc = fminf(fmaxf(x, -kClamp), kClamp);
    float x2 = xc * xc;
    float num = -2.76076847742355e-16f;
    num = fmaf(x2, num, 2.00018790482477e-13f);
    num = fmaf(x2, num, -8.60467152213735e-11f);
    num = fmaf(x2, num, 5.12229709037114e-08f);
    num = fmaf(x2, num, 1.48572235717979e-05f);
    num = fmaf(x2, num, 6.37261928875436e-04f);
    num = fmaf(x2, num, 4.89352455891786e-03f);
    num = xc * num;
    float den = 1.19825839466702e-06f;
    den = fmaf(x2, den, 1.18534705686654e-04f);
    den = fmaf(x2, den, 2.26843463243900e-03f);
    den = fmaf(x2, den, 4.89352518554385e-03f);
    return (fabsf(x) < 0.0004f) ? x : (num / den);
}

// ---------------- Phase 1: mm1[b,t,d] = dx_t @ K[:,d] (raw, no bias) -------
__global__ __launch_bounds__(256, 2)
void lrs_mm1(const float* __restrict__ x, const float* __restrict__ K,
             float* __restrict__ out) {
    const int d = threadIdx.x;
    float kc[128];
#pragma unroll
    for (int j = 0; j < 128; ++j) kc[j] = K[j * 256 + d];

    __shared__ __align__(16) float dx2[2][128];
    const int m0 = blockIdx.x * 256;          // grid 1024, 256 rows/block
    for (int mm = m0; mm < m0 + 256; mm += 2) {
        __syncthreads();                      // protect dx2 reuse
        if (d < 128) {                        // stage row mm
            const float xa  = x[(size_t)mm * 128 + d];
            const float xpa = (mm & 1023) ? x[(size_t)(mm - 1) * 128 + d] : 0.0f;
            dx2[0][d] = xa - xpa;             // f32 sub (= ref)
        } else {                              // stage row mm+1
            const int dd = d - 128;
            const float xb  = x[(size_t)(mm + 1) * 128 + dd];
            const float xpb = ((mm + 1) & 1023) ? x[(size_t)mm * 128 + dd] : 0.0f;
            dx2[1][dd] = xb - xpb;
        }
        __syncthreads();

        float a0 = 0.0f, a1 = 0.0f;
#pragma unroll
        for (int j = 0; j < 128; j += 4) {
            const float4 v0 = *reinterpret_cast<const float4*>(&dx2[0][j]);
            const float4 v1 = *reinterpret_cast<const float4*>(&dx2[1][j]);
            a0 = fmaf(v0.x, kc[j + 0], a0);  a1 = fmaf(v1.x, kc[j + 0], a1);
            a0 = fmaf(v0.y, kc[j + 1], a0);  a1 = fmaf(v1.y, kc[j + 1], a1);
            a0 = fmaf(v0.z, kc[j + 2], a0);  a1 = fmaf(v1.z, kc[j + 2], a1);
            a0 = fmaf(v0.w, kc[j + 3], a0);  a1 = fmaf(v1.w, kc[j + 3], a1);
        }
        out[(size_t)mm * 256 + d]       = a0;
        out[(size_t)(mm + 1) * 256 + d] = a1;
    }
}

// ---------------- Phase 2: recurrence (asm-pinned LDS pipeline) -------------
// asm helpers: DSR issues a broadcast ds_read_b128; WT is a counted wait +
// scheduler fence (keeps hipcc from hoisting dependent FMAs past the wait).
#define DSR(W, N) asm volatile("ds_read_b128 %0, %1 offset:" #N \
                               : "=v"(W) : "v"(dhb));
#define WT(N)     asm volatile("s_waitcnt lgkmcnt(" #N ")" ::: "memory"); \
                  __builtin_amdgcn_sched_barrier(0);
#define F4(W, G) \
    acc = fmaf(W.x, rcf[4*(G)+0], acc); \
    acc = fmaf(W.y, rcf[4*(G)+1], acc); \
    acc = fmaf(W.z, rcf[4*(G)+2], acc); \
    acc = fmaf(W.w, rcf[4*(G)+3], acc);
#define GF(W, G, OFF)  WT(11) F4(W, G) DSR(W, OFF)      // steady-state group
#define GT(W, G, CNT)  WT(CNT) F4(W, G)                  // tail group

#define STEP(DHB, H1C, DHN, H1N, T)                                          \
{                                                                            \
    const float u1n = ((T) < 1023) ? orow[((T) + 1) * 256 + d] : 0.0f;       \
    const float sh  = (d < 64) ? 1.0f : H1C[d - 64];                         \
    const unsigned dhb = (DHB);                                              \
    float4 w0, w1, w2, w3, w4, w5, w6, w7, w8, w9, w10, w11;                 \
    DSR(w0, 0)    DSR(w1, 16)   DSR(w2, 32)   DSR(w3, 48)                    \
    DSR(w4, 64)   DSR(w5, 80)   DSR(w6, 96)   DSR(w7, 112)                   \
    DSR(w8, 128)  DSR(w9, 144)  DSR(w10, 160) DSR(w11, 176)                  \
    float acc = 0.0f;                                                        \
    GF(w0,  0, 192)  GF(w1,  1, 208)  GF(w2,  2, 224)  GF(w3,  3, 240)      \
    GF(w4,  4, 256)  GF(w5,  5, 272)  GF(w6,  6, 288)  GF(w7,  7, 304)      \
    GF(w8,  8, 320)  GF(w9,  9, 336)  GF(w10, 10, 352) GF(w11, 11, 368)     \
    GF(w0, 12, 384)  GF(w1, 13, 400)  GF(w2, 14, 416)  GF(w3, 15, 432)      \
    GF(w4, 16, 448)  GF(w5, 17, 464)  GF(w6, 18, 480)  GF(w7, 19, 496)      \
    GF(w8, 20, 512)  GF(w9, 21, 528)  GF(w10, 22, 544) GF(w11, 23, 560)     \
    GF(w0, 24, 576)  GF(w1, 25, 592)  GF(w2, 26, 608)  GF(w3, 27, 624)      \
    GF(w4, 28, 640)  GF(w5, 29, 656)  GF(w6, 30, 672)  GF(w7, 31, 688)      \
    GF(w8, 32, 704)  GF(w9, 33, 720)  GF(w10, 34, 736) GF(w11, 35, 752)     \
    GF(w0, 36, 768)  GF(w1, 37, 784)  GF(w2, 38, 800)  GF(w3, 39, 816)      \
    GF(w4, 40, 832)  GF(w5, 41, 848)  GF(w6, 42, 864)  GF(w7, 43, 880)      \
    GF(w8, 44, 896)  GF(w9, 45, 912)  GF(w10, 46, 928) GF(w11, 47, 944)     \
    GF(w0, 48, 960)  GF(w1, 49, 976)  GF(w2, 50, 992)  GF(w3, 51, 1008)     \
    GT(w4, 52, 11)   GT(w5, 53, 10)   GT(w6, 54, 9)    GT(w7, 55, 8)        \
    GT(w8, 56, 7)    GT(w9, 57, 6)    GT(w10, 58, 5)   GT(w11, 59, 4)       \
    GT(w0, 60, 3)    GT(w1, 61, 2)    GT(w2, 62, 1)    GT(w3, 63, 0)        \
    const float u  = (u1 + acc) + bd;                                        \
    const float z  = fmaf(sh, u, h1);                                        \
    const float hn = xla_tanh(z);                                            \
    DHN[d] = hn - h1;                                                        \
    H1N[d] = hn;                                                             \
    orow[(T) * 256 + d] = hn;                                                \
    h1 = hn; u1 = u1n;                                                       \
    __syncthreads();                                                         \
}

__global__ __launch_bounds__(256, 1)
void lrs_rec(const float* __restrict__ R, const float* __restrict__ bias,
             float* __restrict__ out) {
    const int b = blockIdx.x;      // grid = 256, one batch row per block/CU
    const int d = threadIdx.x;     // one output column per thread

    __shared__ __align__(16) float dh0[256], dh1[256];
    __shared__ __align__(16) float h10[256], h11[256];

    float rcf[256];                // R[:,d]; compiler splits VGPR/AGPR
#pragma unroll
    for (int i = 0; i < 256; ++i) rcf[i] = R[(size_t)i * 256 + d];
    const float bd = bias[d];      // zeros in this problem

    dh0[d] = 0.0f;
    h10[d] = 0.0f;
    float h1 = 0.0f;
    __syncthreads();

    float* orow = out + (size_t)b * (1024 * 256);
    float u1 = orow[d];            // mm1 for t=0 (phase-1 result)

    // LDS byte offsets of the two dh buffers (shared aperture is 4GB-aligned:
    // low 32 bits of the generic address = LDS offset)
    const unsigned dhb0 = (unsigned)(uintptr_t)(void*)dh0;
    const unsigned dhb1 = (unsigned)(uintptr_t)(void*)dh1;

    for (int t = 0; t < 1024; t += 2) {
        STEP(dhb0, h10, dh1, h11, t)
        STEP(dhb1, h11, dh0, h10, t + 1)
    }
}

#undef STEP
#undef GF
#undef GT
#undef F4
#undef WT
#undef DSR

extern "C" void kernel_launch(void* const* d_in, const int* in_sizes, int n_in,
                              void* d_out, int out_size, void* d_ws, size_t ws_size,
                              hipStream_t stream) {
    // Size-based mapping (element counts); fallback to dict order.
    const float* x = nullptr; const float* K = nullptr;
    const float* R = nullptr; const float* bias = nullptr;
    for (int i = 0; i < n_in; ++i) {
        switch (in_sizes[i]) {
            case 33554432: x    = (const float*)d_in[i]; break;
            case 32768:    K    = (const float*)d_in[i]; break;
            case 65536:    R    = (const float*)d_in[i]; break;
            case 256:      bias = (const float*)d_in[i]; break;
            default: break;
        }
    }
    if (!x || !K || !R || !bias) {
        x    = (const float*)d_in[0];
        K    = (const float*)d_in[1];
        R    = (const float*)d_in[2];
        bias = (const float*)d_in[3];
    }
    float* out = (float*)d_out;

    lrs_mm1<<<1024, 256, 0, stream>>>(x, K, out);
    lrs_rec<<<256, 256, 0, stream>>>(R, bias, out);
}

// Round 27
// 1636.303 us; speedup vs baseline: 1.7926x; 1.0182x over previous
//
#include <hip/hip_runtime.h>
#include <hip/hip_bf16.h>
#include <math.h>

// Shapes: B=256, T=1024, F=128, D=256, UNITS=64. Inputs f32; out f32 [B,T,D].
//
// FROZEN arithmetic (r17+, absmax=0.0 bit-exact): sequential ascending-k fmaf
// chains, u=(mm1+mm2)+bias, z=fmaf(sh,u,h1), XLA EmitFastTanh.
// Delivery-cost model (r19-r26): any uniform fan-out costs ~8cyc/4 values:
// b128 broadcast -> DS pipe (~2048 cyc full delivery, r26), readlane -> VALU
// port (~2048 cyc, r21). r27: SPLIT delivery across both ports so they
// overlap: elems 0..127 via r26's asm-pinned 12-deep b128 window (DS),
// elems 128..255 via r21's readlane groups (VALU). Chain order unchanged.

__device__ __forceinline__ float xla_tanh(float x) {
    const float kClamp = 7.99881172180175781f;
    float xc = fminf(fmaxf(x, -kClamp), kClamp);
    float x2 = xc * xc;
    float num = -2.76076847742355e-16f;
    num = fmaf(x2, num, 2.00018790482477e-13f);
    num = fmaf(x2, num, -8.60467152213735e-11f);
    num = fmaf(x2, num, 5.12229709037114e-08f);
    num = fmaf(x2, num, 1.48572235717979e-05f);
    num = fmaf(x2, num, 6.37261928875436e-04f);
    num = fmaf(x2, num, 4.89352455891786e-03f);
    num = xc * num;
    float den = 1.19825839466702e-06f;
    den = fmaf(x2, den, 1.18534705686654e-04f);
    den = fmaf(x2, den, 2.26843463243900e-03f);
    den = fmaf(x2, den, 4.89352518554385e-03f);
    return (fabsf(x) < 0.0004f) ? x : (num / den);
}

// ---------------- Phase 1: mm1[b,t,d] = dx_t @ K[:,d] (raw, no bias) -------
__global__ __launch_bounds__(256, 2)
void lrs_mm1(const float* __restrict__ x, const float* __restrict__ K,
             float* __restrict__ out) {
    const int d = threadIdx.x;
    float kc[128];
#pragma unroll
    for (int j = 0; j < 128; ++j) kc[j] = K[j * 256 + d];

    __shared__ __align__(16) float dx2[2][128];
    const int m0 = blockIdx.x * 256;          // grid 1024, 256 rows/block
    for (int mm = m0; mm < m0 + 256; mm += 2) {
        __syncthreads();                      // protect dx2 reuse
        if (d < 128) {                        // stage row mm
            const float xa  = x[(size_t)mm * 128 + d];
            const float xpa = (mm & 1023) ? x[(size_t)(mm - 1) * 128 + d] : 0.0f;
            dx2[0][d] = xa - xpa;             // f32 sub (= ref)
        } else {                              // stage row mm+1
            const int dd = d - 128;
            const float xb  = x[(size_t)(mm + 1) * 128 + dd];
            const float xpb = ((mm + 1) & 1023) ? x[(size_t)mm * 128 + dd] : 0.0f;
            dx2[1][dd] = xb - xpb;
        }
        __syncthreads();

        float a0 = 0.0f, a1 = 0.0f;
#pragma unroll
        for (int j = 0; j < 128; j += 4) {
            const float4 v0 = *reinterpret_cast<const float4*>(&dx2[0][j]);
            const float4 v1 = *reinterpret_cast<const float4*>(&dx2[1][j]);
            a0 = fmaf(v0.x, kc[j + 0], a0);  a1 = fmaf(v1.x, kc[j + 0], a1);
            a0 = fmaf(v0.y, kc[j + 1], a0);  a1 = fmaf(v1.y, kc[j + 1], a1);
            a0 = fmaf(v0.z, kc[j + 2], a0);  a1 = fmaf(v1.z, kc[j + 2], a1);
            a0 = fmaf(v0.w, kc[j + 3], a0);  a1 = fmaf(v1.w, kc[j + 3], a1);
        }
        out[(size_t)mm * 256 + d]       = a0;
        out[(size_t)(mm + 1) * 256 + d] = a1;
    }
}

// ---------------- Phase 2: recurrence (hybrid delivery) ---------------------
__device__ __forceinline__ float rdlane(float v, int l) {
    return __uint_as_float(__builtin_amdgcn_readlane(__float_as_uint(v), l));
}

#define DSR(W, N) asm volatile("ds_read_b128 %0, %1 offset:" #N \
                               : "=v"(W) : "v"(dhb));
#define WT(N)     asm volatile("s_waitcnt lgkmcnt(" #N ")" ::: "memory"); \
                  __builtin_amdgcn_sched_barrier(0);
#define F4(W, G) \
    acc = fmaf(W.x, rcf[4*(G)+0], acc); \
    acc = fmaf(W.y, rcf[4*(G)+1], acc); \
    acc = fmaf(W.z, rcf[4*(G)+2], acc); \
    acc = fmaf(W.w, rcf[4*(G)+3], acc);
#define GF(W, G, OFF)  WT(11) F4(W, G) DSR(W, OFF)       // steady (refill)
#define GT(W, G, CNT)  WT(CNT) F4(W, G)                   // tail (drain)
// readlane chunk: 64 elements, groups of 8 prefetched (r21-proven)
#define CHUNK(C, OFF)                                                         \
    _Pragma("unroll")                                                         \
    for (int g = 0; g < 8; ++g) {                                             \
        const int i0 = g * 8;                                                 \
        const float m0 = rdlane(C, i0 + 0);                                   \
        const float m1 = rdlane(C, i0 + 1);                                   \
        const float m2 = rdlane(C, i0 + 2);                                   \
        const float m3 = rdlane(C, i0 + 3);                                   \
        const float m4 = rdlane(C, i0 + 4);                                   \
        const float m5 = rdlane(C, i0 + 5);                                   \
        const float m6 = rdlane(C, i0 + 6);                                   \
        const float m7 = rdlane(C, i0 + 7);                                   \
        acc = fmaf(m0, rcf[(OFF) + i0 + 0], acc);                             \
        acc = fmaf(m1, rcf[(OFF) + i0 + 1], acc);                             \
        acc = fmaf(m2, rcf[(OFF) + i0 + 2], acc);                             \
        acc = fmaf(m3, rcf[(OFF) + i0 + 3], acc);                             \
        acc = fmaf(m4, rcf[(OFF) + i0 + 4], acc);                             \
        acc = fmaf(m5, rcf[(OFF) + i0 + 5], acc);                             \
        acc = fmaf(m6, rcf[(OFF) + i0 + 6], acc);                             \
        acc = fmaf(m7, rcf[(OFF) + i0 + 7], acc);                             \
    }

#define STEP(DHC, DHB, H1C, DHN, H1N, T)                                      \
{                                                                             \
    const float u1n = ((T) < 1023) ? orow[((T) + 1) * 256 + d] : 0.0f;        \
    const float sh  = (d < 64) ? 1.0f : H1C[d - 64];                          \
    const float c2  = DHC[128 + lane];   /* RL sources (per-lane b32) */      \
    const float c3  = DHC[192 + lane];                                        \
    const unsigned dhb = (DHB);                                               \
    float4 w0, w1, w2, w3, w4, w5, w6, w7, w8, w9, w10, w11;                  \
    DSR(w0, 0)    DSR(w1, 16)   DSR(w2, 32)   DSR(w3, 48)                     \
    DSR(w4, 64)   DSR(w5, 80)   DSR(w6, 96)   DSR(w7, 112)                    \
    DSR(w8, 128)  DSR(w9, 144)  DSR(w10, 160) DSR(w11, 176)                   \
    float acc = 0.0f;                                                         \
    /* elements 0..127: 32 groups, 12-deep window (DS pipe) */                \
    GF(w0,  0, 192)  GF(w1,  1, 208)  GF(w2,  2, 224)  GF(w3,  3, 240)        \
    GF(w4,  4, 256)  GF(w5,  5, 272)  GF(w6,  6, 288)  GF(w7,  7, 304)        \
    GF(w8,  8, 320)  GF(w9,  9, 336)  GF(w10, 10, 352) GF(w11, 11, 368)       \
    GF(w0, 12, 384)  GF(w1, 13, 400)  GF(w2, 14, 416)  GF(w3, 15, 432)        \
    GF(w4, 16, 448)  GF(w5, 17, 464)  GF(w6, 18, 480)  GF(w7, 19, 496)        \
    GT(w8, 20, 11)   GT(w9, 21, 10)   GT(w10, 22, 9)   GT(w11, 23, 8)         \
    GT(w0, 24, 7)    GT(w1, 25, 6)    GT(w2, 26, 5)    GT(w3, 27, 4)          \
    GT(w4, 28, 3)    GT(w5, 29, 2)    GT(w6, 30, 1)    GT(w7, 31, 0)          \
    /* elements 128..255: readlane delivery (VALU port) */                    \
    CHUNK(c2, 128)                                                            \
    CHUNK(c3, 192)                                                            \
    const float u  = (u1 + acc) + bd;                                         \
    const float z  = fmaf(sh, u, h1);                                         \
    const float hn = xla_tanh(z);                                             \
    DHN[d] = hn - h1;                                                         \
    H1N[d] = hn;                                                              \
    orow[(T) * 256 + d] = hn;                                                 \
    h1 = hn; u1 = u1n;                                                        \
    __syncthreads();                                                          \
}

__global__ __launch_bounds__(256, 1)
void lrs_rec(const float* __restrict__ R, const float* __restrict__ bias,
             float* __restrict__ out) {
    const int b    = blockIdx.x;   // grid = 256, one batch row per block/CU
    const int d    = threadIdx.x;  // one output column per thread
    const int lane = d & 63;

    __shared__ __align__(16) float dh0[256], dh1[256];
    __shared__ __align__(16) float h10[256], h11[256];

    float rcf[256];                // R[:,d]; compiler splits VGPR/AGPR
#pragma unroll
    for (int i = 0; i < 256; ++i) rcf[i] = R[(size_t)i * 256 + d];
    const float bd = bias[d];      // zeros in this problem

    dh0[d] = 0.0f;
    h10[d] = 0.0f;
    float h1 = 0.0f;
    __syncthreads();

    float* orow = out + (size_t)b * (1024 * 256);
    float u1 = orow[d];            // mm1 for t=0 (phase-1 result)

    const unsigned dhb0 = (unsigned)(uintptr_t)(void*)dh0;
    const unsigned dhb1 = (unsigned)(uintptr_t)(void*)dh1;

    for (int t = 0; t < 1024; t += 2) {
        STEP(dh0, dhb0, h10, dh1, h11, t)
        STEP(dh1, dhb1, h11, dh0, h10, t + 1)
    }
}

#undef STEP
#undef CHUNK
#undef GF
#undef GT
#undef F4
#undef WT
#undef DSR

extern "C" void kernel_launch(void* const* d_in, const int* in_sizes, int n_in,
                              void* d_out, int out_size, void* d_ws, size_t ws_size,
                              hipStream_t stream) {
    // Size-based mapping (element counts); fallback to dict order.
    const float* x = nullptr; const float* K = nullptr;
    const float* R = nullptr; const float* bias = nullptr;
    for (int i = 0; i < n_in; ++i) {
        switch (in_sizes[i]) {
            case 33554432: x    = (const float*)d_in[i]; break;
            case 32768:    K    = (const float*)d_in[i]; break;
            case 65536:    R    = (const float*)d_in[i]; break;
            case 256:      bias = (const float*)d_in[i]; break;
            default: break;
        }
    }
    if (!x || !K || !R || !bias) {
        x    = (const float*)d_in[0];
        K    = (const float*)d_in[1];
        R    = (const float*)d_in[2];
        bias = (const float*)d_in[3];
    }
    float* out = (float*)d_out;

    lrs_mm1<<<1024, 256, 0, stream>>>(x, K, out);
    lrs_rec<<<256, 256, 0, stream>>>(R, bias, out);
}

// Round 28
// 1584.692 us; speedup vs baseline: 1.8509x; 1.0326x over previous
//
#include <hip/hip_runtime.h>
#include <hip/hip_bf16.h>
#include <math.h>

// Shapes: B=256, T=1024, F=128, D=256, UNITS=64. Inputs f32; out f32 [B,T,D].
//
// FROZEN arithmetic (r17+, absmax=0.0 bit-exact): sequential ascending-k fmaf
// chains, u=(mm1+mm2)+bias, z=fmaf(sh,u,h1), XLA EmitFastTanh.
// r27 post-mortem: DS-half THEN RL-half = ports serialized by the single acc
// chain -> no overlap. r28: interleave per 16 ascending indices:
// [8 via readlane (VALU)] + [8 via ds_read_b128 pair (DS pipe, prefetched
// 2 supers ahead, counted lgkmcnt(2))]. Chain order unchanged -> bit-exact.
// All step LDS reads live inside the counted asm stream (5 b32 first,
// WT(4); DS retires in-order) so compiler waits can't interfere.

__device__ __forceinline__ float xla_tanh(float x) {
    const float kClamp = 7.99881172180175781f;
    float xc = fminf(fmaxf(x, -kClamp), kClamp);
    float x2 = xc * xc;
    float num = -2.76076847742355e-16f;
    num = fmaf(x2, num, 2.00018790482477e-13f);
    num = fmaf(x2, num, -8.60467152213735e-11f);
    num = fmaf(x2, num, 5.12229709037114e-08f);
    num = fmaf(x2, num, 1.48572235717979e-05f);
    num = fmaf(x2, num, 6.37261928875436e-04f);
    num = fmaf(x2, num, 4.89352455891786e-03f);
    num = xc * num;
    float den = 1.19825839466702e-06f;
    den = fmaf(x2, den, 1.18534705686654e-04f);
    den = fmaf(x2, den, 2.26843463243900e-03f);
    den = fmaf(x2, den, 4.89352518554385e-03f);
    return (fabsf(x) < 0.0004f) ? x : (num / den);
}

// ---------------- Phase 1: mm1[b,t,d] = dx_t @ K[:,d] (raw, no bias) -------
__global__ __launch_bounds__(256, 2)
void lrs_mm1(const float* __restrict__ x, const float* __restrict__ K,
             float* __restrict__ out) {
    const int d = threadIdx.x;
    float kc[128];
#pragma unroll
    for (int j = 0; j < 128; ++j) kc[j] = K[j * 256 + d];

    __shared__ __align__(16) float dx2[2][128];
    const int m0 = blockIdx.x * 256;          // grid 1024, 256 rows/block
    for (int mm = m0; mm < m0 + 256; mm += 2) {
        __syncthreads();                      // protect dx2 reuse
        if (d < 128) {                        // stage row mm
            const float xa  = x[(size_t)mm * 128 + d];
            const float xpa = (mm & 1023) ? x[(size_t)(mm - 1) * 128 + d] : 0.0f;
            dx2[0][d] = xa - xpa;             // f32 sub (= ref)
        } else {                              // stage row mm+1
            const int dd = d - 128;
            const float xb  = x[(size_t)(mm + 1) * 128 + dd];
            const float xpb = ((mm + 1) & 1023) ? x[(size_t)mm * 128 + dd] : 0.0f;
            dx2[1][dd] = xb - xpb;
        }
        __syncthreads();

        float a0 = 0.0f, a1 = 0.0f;
#pragma unroll
        for (int j = 0; j < 128; j += 4) {
            const float4 v0 = *reinterpret_cast<const float4*>(&dx2[0][j]);
            const float4 v1 = *reinterpret_cast<const float4*>(&dx2[1][j]);
            a0 = fmaf(v0.x, kc[j + 0], a0);  a1 = fmaf(v1.x, kc[j + 0], a1);
            a0 = fmaf(v0.y, kc[j + 1], a0);  a1 = fmaf(v1.y, kc[j + 1], a1);
            a0 = fmaf(v0.z, kc[j + 2], a0);  a1 = fmaf(v1.z, kc[j + 2], a1);
            a0 = fmaf(v0.w, kc[j + 3], a0);  a1 = fmaf(v1.w, kc[j + 3], a1);
        }
        out[(size_t)mm * 256 + d]       = a0;
        out[(size_t)(mm + 1) * 256 + d] = a1;
    }
}

// ---------------- Phase 2: recurrence (interleaved dual-port delivery) ------
__device__ __forceinline__ float rdlane(float v, int l) {
    return __uint_as_float(__builtin_amdgcn_readlane(__float_as_uint(v), l));
}

#define DSR32(W, A, N) asm volatile("ds_read_b32 %0, %1 offset:" #N \
                                    : "=v"(W) : "v"(A));
#define DSR(W, N) asm volatile("ds_read_b128 %0, %1 offset:" #N \
                               : "=v"(W) : "v"(dhb));
#define WT(N)     asm volatile("s_waitcnt lgkmcnt(" #N ")" ::: "memory"); \
                  __builtin_amdgcn_sched_barrier(0);

// One 16-index super-block: 8 RL-delivered + 8 DS-delivered (one b128 pair),
// single ascending acc chain (bit-exact). WTN = wait count before DS pair use.
#define SUP(C, LB, I, W0, W1, WTN)                                            \
    {                                                                         \
        const float m0 = rdlane(C, (LB) + 0);                                 \
        const float m1 = rdlane(C, (LB) + 1);                                 \
        const float m2 = rdlane(C, (LB) + 2);                                 \
        const float m3 = rdlane(C, (LB) + 3);                                 \
        const float m4 = rdlane(C, (LB) + 4);                                 \
        const float m5 = rdlane(C, (LB) + 5);                                 \
        const float m6 = rdlane(C, (LB) + 6);                                 \
        const float m7 = rdlane(C, (LB) + 7);                                 \
        acc = fmaf(m0, rcf[(I) + 0], acc);                                    \
        acc = fmaf(m1, rcf[(I) + 1], acc);                                    \
        acc = fmaf(m2, rcf[(I) + 2], acc);                                    \
        acc = fmaf(m3, rcf[(I) + 3], acc);                                    \
        acc = fmaf(m4, rcf[(I) + 4], acc);                                    \
        acc = fmaf(m5, rcf[(I) + 5], acc);                                    \
        acc = fmaf(m6, rcf[(I) + 6], acc);                                    \
        acc = fmaf(m7, rcf[(I) + 7], acc);                                    \
    }                                                                         \
    WT(WTN)                                                                   \
    acc = fmaf(W0.x, rcf[(I) + 8],  acc);                                     \
    acc = fmaf(W0.y, rcf[(I) + 9],  acc);                                     \
    acc = fmaf(W0.z, rcf[(I) + 10], acc);                                     \
    acc = fmaf(W0.w, rcf[(I) + 11], acc);                                     \
    acc = fmaf(W1.x, rcf[(I) + 12], acc);                                     \
    acc = fmaf(W1.y, rcf[(I) + 13], acc);                                     \
    acc = fmaf(W1.z, rcf[(I) + 14], acc);                                     \
    acc = fmaf(W1.w, rcf[(I) + 15], acc);

#define STEP(ADH, AH1, DHB, DHN, H1N, T)                                      \
{                                                                             \
    const float u1n = ((T) < 1023) ? orow[((T) + 1) * 256 + d] : 0.0f;        \
    const unsigned dhb = (DHB);                                               \
    float c0v, c1v, c2v, c3v, shv;                                            \
    float4 wA0, wA1, wB0, wB1;                                                \
    DSR32(c0v, (ADH), 0)   DSR32(c1v, (ADH), 256)                             \
    DSR32(c2v, (ADH), 512) DSR32(c3v, (ADH), 768)                             \
    DSR32(shv, (AH1), 0)                                                      \
    DSR(wA0, 32) DSR(wA1, 48) DSR(wB0, 96) DSR(wB1, 112)                      \
    WT(4)  /* 5 b32 done (in-order); 4 b128 in flight */                      \
    const float sh = (d < 64) ? 1.0f : shv;                                   \
    float acc = 0.0f;                                                         \
    SUP(c0v,  0,   0, wA0, wA1, 2) DSR(wA0, 160) DSR(wA1, 176)                \
    SUP(c0v, 16,  16, wB0, wB1, 2) DSR(wB0, 224) DSR(wB1, 240)                \
    SUP(c0v, 32,  32, wA0, wA1, 2) DSR(wA0, 288) DSR(wA1, 304)                \
    SUP(c0v, 48,  48, wB0, wB1, 2) DSR(wB0, 352) DSR(wB1, 368)                \
    SUP(c1v,  0,  64, wA0, wA1, 2) DSR(wA0, 416) DSR(wA1, 432)                \
    SUP(c1v, 16,  80, wB0, wB1, 2) DSR(wB0, 480) DSR(wB1, 496)                \
    SUP(c1v, 32,  96, wA0, wA1, 2) DSR(wA0, 544) DSR(wA1, 560)                \
    SUP(c1v, 48, 112, wB0, wB1, 2) DSR(wB0, 608) DSR(wB1, 624)                \
    SUP(c2v,  0, 128, wA0, wA1, 2) DSR(wA0, 672) DSR(wA1, 688)                \
    SUP(c2v, 16, 144, wB0, wB1, 2) DSR(wB0, 736) DSR(wB1, 752)                \
    SUP(c2v, 32, 160, wA0, wA1, 2) DSR(wA0, 800) DSR(wA1, 816)                \
    SUP(c2v, 48, 176, wB0, wB1, 2) DSR(wB0, 864) DSR(wB1, 880)                \
    SUP(c3v,  0, 192, wA0, wA1, 2) DSR(wA0, 928) DSR(wA1, 944)                \
    SUP(c3v, 16, 208, wB0, wB1, 2) DSR(wB0, 992) DSR(wB1, 1008)               \
    SUP(c3v, 32, 224, wA0, wA1, 2)  /* s=14: no refill */                     \
    SUP(c3v, 48, 240, wB0, wB1, 0)  /* s=15: drain */                         \
    const float u  = (u1 + acc) + bd;                                         \
    const float z  = fmaf(sh, u, h1);                                         \
    const float hn = xla_tanh(z);                                             \
    DHN[d] = hn - h1;                                                         \
    H1N[d] = hn;                                                              \
    orow[(T) * 256 + d] = hn;                                                 \
    h1 = hn; u1 = u1n;                                                        \
    __syncthreads();                                                          \
}

__global__ __launch_bounds__(256, 1)
void lrs_rec(const float* __restrict__ R, const float* __restrict__ bias,
             float* __restrict__ out) {
    const int b    = blockIdx.x;   // grid = 256, one batch row per block/CU
    const int d    = threadIdx.x;  // one output column per thread
    const int lane = d & 63;

    __shared__ __align__(16) float dh0[256], dh1[256];
    __shared__ __align__(16) float h10[256], h11[256];

    float rcf[256];                // R[:,d]; compiler splits VGPR/AGPR
#pragma unroll
    for (int i = 0; i < 256; ++i) rcf[i] = R[(size_t)i * 256 + d];
    const float bd = bias[d];      // zeros in this problem

    dh0[d] = 0.0f;
    h10[d] = 0.0f;
    float h1 = 0.0f;
    __syncthreads();

    float* orow = out + (size_t)b * (1024 * 256);
    float u1 = orow[d];            // mm1 for t=0 (phase-1 result)

    // LDS byte addresses (shared aperture: low 32 bits = LDS offset)
    const unsigned dhb0 = (unsigned)(uintptr_t)(void*)dh0;
    const unsigned dhb1 = (unsigned)(uintptr_t)(void*)dh1;
    const unsigned adh0 = dhb0 + 4u * (unsigned)lane;          // c-src reads
    const unsigned adh1 = dhb1 + 4u * (unsigned)lane;
    const unsigned ah10 = (unsigned)(uintptr_t)(void*)h10 +
                          4u * (((unsigned)d + 192u) & 255u);  // shift read
    const unsigned ah11 = (unsigned)(uintptr_t)(void*)h11 +
                          4u * (((unsigned)d + 192u) & 255u);

    for (int t = 0; t < 1024; t += 2) {
        STEP(adh0, ah10, dhb0, dh1, h11, t)
        STEP(adh1, ah11, dhb1, dh0, h10, t + 1)
    }
}

#undef STEP
#undef SUP
#undef WT
#undef DSR
#undef DSR32

extern "C" void kernel_launch(void* const* d_in, const int* in_sizes, int n_in,
                              void* d_out, int out_size, void* d_ws, size_t ws_size,
                              hipStream_t stream) {
    // Size-based mapping (element counts); fallback to dict order.
    const float* x = nullptr; const float* K = nullptr;
    const float* R = nullptr; const float* bias = nullptr;
    for (int i = 0; i < n_in; ++i) {
        switch (in_sizes[i]) {
            case 33554432: x    = (const float*)d_in[i]; break;
            case 32768:    K    = (const float*)d_in[i]; break;
            case 65536:    R    = (const float*)d_in[i]; break;
            case 256:      bias = (const float*)d_in[i]; break;
            default: break;
        }
    }
    if (!x || !K || !R || !bias) {
        x    = (const float*)d_in[0];
        K    = (const float*)d_in[1];
        R    = (const float*)d_in[2];
        bias = (const float*)d_in[3];
    }
    float* out = (float*)d_out;

    lrs_mm1<<<1024, 256, 0, stream>>>(x, K, out);
    lrs_rec<<<256, 256, 0, stream>>>(R, bias, out);
}